// Round 2
// baseline (533.874 us; speedup 1.0000x reference)
//
#include <hip/hip_runtime.h>

// GNN layer: messages = relu(NF @ Wm^T + bm); agg = (adj @ messages)/deg; GRU(agg, NF)
// N=8192, D=128. Memory-bound on adj (268 MB int32) -> floor ~43 us.
// k2 is barrier-free + LDS-free: per-wave 16-row adj strip, A-frags built in
// registers from int4 adj loads, B-frags straight from L2-resident msgT.

#define NN 8192
#define DIM 128
#define LSTR 136  // LDS row stride in shorts (128 + 8 pad), 16B-aligned rows

typedef __bf16 bf16x8 __attribute__((ext_vector_type(8)));
typedef float f32x4 __attribute__((ext_vector_type(4)));

__device__ __forceinline__ unsigned short f2bf(float f) {
  union { float f; unsigned u; } v; v.f = f;
  unsigned r = v.u + 0x7FFF + ((v.u >> 16) & 1);  // RNE
  return (unsigned short)(r >> 16);
}
__device__ __forceinline__ float sigmoidf_(float x) {
  return 1.0f / (1.0f + __expf(-x));
}
__device__ __forceinline__ float tanhf_(float x) {
  float e = __expf(-2.0f * fabsf(x));
  float r = (1.0f - e) / (1.0f + e);
  return x < 0.0f ? -r : r;
}
__device__ __forceinline__ void pack4(float4 v, unsigned short* dst) {
  dst[0] = f2bf(v.x); dst[1] = f2bf(v.y); dst[2] = f2bf(v.z); dst[3] = f2bf(v.w);
}

// ---------------- K1: msgT[o][m] = relu(NF @ Wm^T + bm) bf16, coalesced via LDS transpose
__global__ __launch_bounds__(256) void k1_msg(
    const float* __restrict__ nf, const float* __restrict__ w_msg,
    const float* __restrict__ b_msg, unsigned short* __restrict__ msgT) {
  __shared__ unsigned short wm[128 * LSTR];   // wm[o][k]; later reused as T[o][m] (stride 72)
  __shared__ unsigned short nfl[64 * LSTR];   // nf tile [m][k]
  const int t = threadIdx.x;
  const int m0 = blockIdx.x * 64;
  const float4* wm4 = (const float4*)w_msg;
  const float4* nf4 = (const float4*)nf;
  for (int i = t; i < 4096; i += 256) {       // 128x128 weights
    float4 v = wm4[i];
    pack4(v, &wm[(i >> 5) * LSTR + (i & 31) * 4]);
  }
  for (int i = t; i < 2048; i += 256) {       // 64x128 nf rows
    float4 v = nf4[m0 * 32 + i];
    pack4(v, &nfl[(i >> 5) * LSTR + (i & 31) * 4]);
  }
  __syncthreads();
  const int lane = t & 63, wave = t >> 6;
  const int quad = lane >> 4, l16 = lane & 15;
  const int rt = wave;  // 4 waves x 16 rows
  f32x4 acc[8];
  for (int j = 0; j < 8; ++j) acc[j] = (f32x4){0.f, 0.f, 0.f, 0.f};
  for (int kk = 0; kk < 4; ++kk) {
    bf16x8 a = *(const bf16x8*)&nfl[(rt * 16 + l16) * LSTR + kk * 32 + quad * 8];
    for (int ct = 0; ct < 8; ++ct) {
      bf16x8 b = *(const bf16x8*)&wm[(ct * 16 + l16) * LSTR + kk * 32 + quad * 8];
      acc[ct] = __builtin_amdgcn_mfma_f32_16x16x32_bf16(a, b, acc[ct], 0, 0, 0);
    }
  }
  __syncthreads();  // all frag reads of wm done; reuse wm as transpose tile T[128][72]
  for (int ct = 0; ct < 8; ++ct) {
    const int o = ct * 16 + l16;
    const float bias = b_msg[o];
    for (int r = 0; r < 4; ++r) {
      const int mloc = rt * 16 + quad * 4 + r;
      wm[o * 72 + mloc] = f2bf(fmaxf(acc[ct][r] + bias, 0.0f));
    }
  }
  __syncthreads();
  for (int i = t; i < 1024; i += 256) {       // 128 rows x 8 int4 (64 shorts) each
    const int o = i >> 3, seg = i & 7;
    *(int4*)&msgT[o * NN + m0 + seg * 8] = *(const int4*)&wm[o * 72 + seg * 8];
  }
}

// ---------------- K2: barrier-free, LDS-free. part[split][m][o] fp32, degp[split][m].
// Grid 512 blocks x 256 thr; block = one 16-row strip, wave w = K-split w (2048 k each).
__global__ __launch_bounds__(256, 2) void k2_agg(
    const int* __restrict__ adj, const unsigned short* __restrict__ msgT,
    float* __restrict__ part, int* __restrict__ degp) {
  const int t = threadIdx.x;
  const int lane = t & 63, split = t >> 6;
  const int quad = lane >> 4, l16 = lane & 15;
  const int strip = blockIdx.x;
  const int row = strip * 16 + l16;
  const int kb = split * 2048;

  const int* aP = adj + (size_t)row * NN + kb + quad * 8;
  const unsigned short* mB = msgT + (size_t)l16 * NN + kb + quad * 8;

  f32x4 acc[8];
  for (int j = 0; j < 8; ++j) acc[j] = (f32x4){0.f, 0.f, 0.f, 0.f};
  int deg = 0;

  int4 cA0 = *(const int4*)aP;
  int4 cA1 = *(const int4*)(aP + 4);
  bf16x8 cB[8];
#pragma unroll
  for (int ct = 0; ct < 8; ++ct) cB[ct] = *(const bf16x8*)(mB + ct * 16 * NN);
  int4 nA0 = cA0, nA1 = cA1;
  bf16x8 nB[8];

  for (int s = 0; s < 64; ++s) {
    if (s < 63) {  // prefetch next 32-k step; no barrier anywhere -> stays in flight
      const int ko = (s + 1) * 32;
      nA0 = *(const int4*)(aP + ko);
      nA1 = *(const int4*)(aP + ko + 4);
#pragma unroll
      for (int ct = 0; ct < 8; ++ct)
        nB[ct] = *(const bf16x8*)(mB + ct * 16 * NN + ko);
    }
    union { bf16x8 v; unsigned short s[8]; } a;
    a.s[0] = cA0.x ? 0x3F80 : 0; a.s[1] = cA0.y ? 0x3F80 : 0;
    a.s[2] = cA0.z ? 0x3F80 : 0; a.s[3] = cA0.w ? 0x3F80 : 0;
    a.s[4] = cA1.x ? 0x3F80 : 0; a.s[5] = cA1.y ? 0x3F80 : 0;
    a.s[6] = cA1.z ? 0x3F80 : 0; a.s[7] = cA1.w ? 0x3F80 : 0;
    deg += cA0.x + cA0.y + cA0.z + cA0.w + cA1.x + cA1.y + cA1.z + cA1.w;
#pragma unroll
    for (int ct = 0; ct < 8; ++ct)
      acc[ct] = __builtin_amdgcn_mfma_f32_16x16x32_bf16(a.v, cB[ct], acc[ct], 0, 0, 0);
    cA0 = nA0; cA1 = nA1;
#pragma unroll
    for (int ct = 0; ct < 8; ++ct) cB[ct] = nB[ct];
  }
  // degree: lanes {l16, l16+16, l16+32, l16+48} hold quad-partials of row l16
  deg += __shfl_xor(deg, 16, 64);
  deg += __shfl_xor(deg, 32, 64);
  if (lane < 16) degp[split * NN + strip * 16 + lane] = deg;
  float* pp = part + (size_t)split * NN * DIM;
#pragma unroll
  for (int ct = 0; ct < 8; ++ct)
    for (int r = 0; r < 4; ++r)
      pp[(strip * 16 + quad * 4 + r) * DIM + ct * 16 + l16] = acc[ct][r];
}

// ---------------- K3: fused GRU; agg assembled from 4 fp32 partials + degree.
__global__ __launch_bounds__(256) void k3_gru(
    const float* __restrict__ nf, const float* __restrict__ part,
    const int* __restrict__ degp,
    const float* __restrict__ w_ih, const float* __restrict__ w_hh,
    const float* __restrict__ b_ih, const float* __restrict__ b_hh,
    float* __restrict__ out) {
  __shared__ unsigned short aggL[32 * LSTR];
  __shared__ unsigned short nfL[32 * LSTR];
  __shared__ unsigned short wL[128 * LSTR];
  __shared__ float invD[32];
  const int t = threadIdx.x;
  const int m0 = blockIdx.x * 32;
  if (t < 32) {
    int d = degp[m0 + t] + degp[NN + m0 + t] + degp[2 * NN + m0 + t] + degp[3 * NN + m0 + t];
    invD[t] = 1.0f / (float)(d > 1 ? d : 1);
  }
  __syncthreads();
  const float4* p4 = (const float4*)part;
  const float4* nf4 = (const float4*)nf;
  for (int u = t; u < 1024; u += 256) {   // 32 rows x 32 float4
    const int m = u >> 5;
    const int gi = (m0 + m) * 32 + (u & 31);
    float4 s0 = p4[gi], s1 = p4[262144 + gi], s2 = p4[524288 + gi], s3 = p4[786432 + gi];
    const float iv = invD[m];
    float4 s;
    s.x = (s0.x + s1.x + s2.x + s3.x) * iv;
    s.y = (s0.y + s1.y + s2.y + s3.y) * iv;
    s.z = (s0.z + s1.z + s2.z + s3.z) * iv;
    s.w = (s0.w + s1.w + s2.w + s3.w) * iv;
    pack4(s, &aggL[m * LSTR + (u & 31) * 4]);
  }
  for (int u = t; u < 1024; u += 256) {
    const int m = u >> 5;
    pack4(nf4[(m0 + m) * 32 + (u & 31)], &nfL[m * LSTR + (u & 31) * 4]);
  }

  const int lane = t & 63, wave = t >> 6;
  const int quad = lane >> 4, l16 = lane & 15;
  const int rt = wave >> 1;
  const int cb = (wave & 1) * 4;
  const int aOff = (rt * 16 + l16) * LSTR + quad * 8;
  const float4* wih4 = (const float4*)w_ih;
  const float4* whh4 = (const float4*)w_hh;

  float gate[4][4];
  const int order[3] = {0, 2, 1};  // r -> n -> z
  for (int ci = 0; ci < 3; ++ci) {
    const int c = order[ci];
    __syncthreads();  // prior wL readers done; first iter: agg/nf staging visible
    for (int u = t; u < 4096; u += 256)
      pack4(wih4[c * 4096 + u], &wL[(u >> 5) * LSTR + (u & 31) * 4]);
    __syncthreads();
    f32x4 ai[4];
    {
      bf16x8 a[4];
      for (int kk = 0; kk < 4; ++kk) a[kk] = *(const bf16x8*)&aggL[aOff + kk * 32];
      for (int j = 0; j < 4; ++j) {
        f32x4 acc = (f32x4){0.f, 0.f, 0.f, 0.f};
        const int ct = cb + j;
        for (int kk = 0; kk < 4; ++kk) {
          bf16x8 b = *(const bf16x8*)&wL[(ct * 16 + l16) * LSTR + kk * 32 + quad * 8];
          acc = __builtin_amdgcn_mfma_f32_16x16x32_bf16(a[kk], b, acc, 0, 0, 0);
        }
        ai[j] = acc;
      }
    }
    __syncthreads();
    for (int u = t; u < 4096; u += 256)
      pack4(whh4[c * 4096 + u], &wL[(u >> 5) * LSTR + (u & 31) * 4]);
    __syncthreads();
    f32x4 ah[4];
    {
      bf16x8 a[4];
      for (int kk = 0; kk < 4; ++kk) a[kk] = *(const bf16x8*)&nfL[aOff + kk * 32];
      for (int j = 0; j < 4; ++j) {
        f32x4 acc = (f32x4){0.f, 0.f, 0.f, 0.f};
        const int ct = cb + j;
        for (int kk = 0; kk < 4; ++kk) {
          bf16x8 b = *(const bf16x8*)&wL[(ct * 16 + l16) * LSTR + kk * 32 + quad * 8];
          acc = __builtin_amdgcn_mfma_f32_16x16x32_bf16(a[kk], b, acc, 0, 0, 0);
        }
        ah[j] = acc;
      }
    }
    for (int j = 0; j < 4; ++j) {
      const int col = (cb + j) * 16 + l16;
      const float bi = b_ih[c * 128 + col];
      const float bh = b_hh[c * 128 + col];
      for (int r = 0; r < 4; ++r) {
        const float gi = ai[j][r] + bi;
        const float gh = ah[j][r] + bh;
        if (c == 0) {
          gate[j][r] = sigmoidf_(gi + gh);
        } else if (c == 2) {
          gate[j][r] = tanhf_(gi + gate[j][r] * gh);
        } else {
          const float z = sigmoidf_(gi + gh);
          const int m = m0 + rt * 16 + quad * 4 + r;
          const float h = nf[m * 128 + col];
          out[m * 128 + col] = (1.0f - z) * gate[j][r] + z * h;
        }
      }
    }
  }
}

extern "C" void kernel_launch(void* const* d_in, const int* in_sizes, int n_in,
                              void* d_out, int out_size, void* d_ws, size_t ws_size,
                              hipStream_t stream) {
  const float* nf   = (const float*)d_in[0];
  const int*   adj  = (const int*)d_in[1];
  const float* wmsg = (const float*)d_in[2];
  const float* bmsg = (const float*)d_in[3];
  const float* wih  = (const float*)d_in[4];
  const float* whh  = (const float*)d_in[5];
  const float* bih  = (const float*)d_in[6];
  const float* bhh  = (const float*)d_in[7];
  float* out = (float*)d_out;

  char* ws = (char*)d_ws;
  unsigned short* msgT = (unsigned short*)ws;                    // bf16 [128][8192]   2 MB
  float* part = (float*)(ws + (size_t)2 * 1024 * 1024);          // f32  [4][8192][128] 16 MB
  int* degp   = (int*)(ws + (size_t)18 * 1024 * 1024);           // int  [4][8192]     128 KB

  k1_msg<<<NN / 64, 256, 0, stream>>>(nf, wmsg, bmsg, msgT);
  k2_agg<<<NN / 16, 256, 0, stream>>>(adj, msgT, part, degp);
  k3_gru<<<NN / 32, 256, 0, stream>>>(nf, part, degp, wih, whh, bih, bhh, out);
}

// Round 3
// 457.725 us; speedup vs baseline: 1.1664x; 1.1664x over previous
//
#include <hip/hip_runtime.h>

// GNN layer: messages = relu(NF @ Wm^T + bm); agg = (adj @ messages)/deg; GRU(agg, NF)
// N=8192, D=128. k2 memory-bound on adj (268 MB) -> ~43 us floor.
// k2 v3: M-tile 64 (4 waves x 16 rows), K-split 8 (range 1024, 16 steps of 64).
// B (msgT) double-buffered in LDS w/ XOR swizzle; A direct int4->frag in regs.
// 1024 blocks = 4/CU, 16 waves/CU. launch_bounds(256,4) keeps VGPR<=128 so the
// prefetch survives (round-2 failed at VGPR=64: one-load-one-wait serial chain).

#define NN 8192
#define DIM 128
#define LSTR 136     // k1/k3 LDS row stride (shorts)
#define KSPLIT 8
#define NSTEP 16     // (8192/KSPLIT)/64 steps of K=64

typedef __bf16 bf16x8 __attribute__((ext_vector_type(8)));
typedef float f32x4 __attribute__((ext_vector_type(4)));

__device__ __forceinline__ unsigned short f2bf(float f) {
  union { float f; unsigned u; } v; v.f = f;
  unsigned r = v.u + 0x7FFF + ((v.u >> 16) & 1);  // RNE
  return (unsigned short)(r >> 16);
}
__device__ __forceinline__ float sigmoidf_(float x) {
  return 1.0f / (1.0f + __expf(-x));
}
__device__ __forceinline__ float tanhf_(float x) {
  float e = __expf(-2.0f * fabsf(x));
  float r = (1.0f - e) / (1.0f + e);
  return x < 0.0f ? -r : r;
}
__device__ __forceinline__ void pack4(float4 v, unsigned short* dst) {
  dst[0] = f2bf(v.x); dst[1] = f2bf(v.y); dst[2] = f2bf(v.z); dst[3] = f2bf(v.w);
}
// k2 LDS B-tile addressing: row o (128), 8 chunks of 8 shorts (K=64), XOR swizzle
__device__ __forceinline__ int ldsOff(int o, int chunk) {
  return o * 64 + ((chunk ^ (o & 7)) << 3);
}

// ---------------- K1: msgT[o][m] = relu(NF @ Wm^T + bm) bf16, coalesced stores
__global__ __launch_bounds__(256) void k1_msg(
    const float* __restrict__ nf, const float* __restrict__ w_msg,
    const float* __restrict__ b_msg, unsigned short* __restrict__ msgT) {
  __shared__ unsigned short wm[128 * LSTR];   // wm[o][k]; reused as T[o][m] (stride 72)
  __shared__ unsigned short nfl[64 * LSTR];
  const int t = threadIdx.x;
  const int m0 = blockIdx.x * 64;
  const float4* wm4 = (const float4*)w_msg;
  const float4* nf4 = (const float4*)nf;
  for (int i = t; i < 4096; i += 256)
    pack4(wm4[i], &wm[(i >> 5) * LSTR + (i & 31) * 4]);
  for (int i = t; i < 2048; i += 256)
    pack4(nf4[m0 * 32 + i], &nfl[(i >> 5) * LSTR + (i & 31) * 4]);
  __syncthreads();
  const int lane = t & 63, wave = t >> 6;
  const int quad = lane >> 4, l16 = lane & 15;
  const int rt = wave;
  f32x4 acc[8];
  for (int j = 0; j < 8; ++j) acc[j] = (f32x4){0.f, 0.f, 0.f, 0.f};
  for (int kk = 0; kk < 4; ++kk) {
    bf16x8 a = *(const bf16x8*)&nfl[(rt * 16 + l16) * LSTR + kk * 32 + quad * 8];
    for (int ct = 0; ct < 8; ++ct) {
      bf16x8 b = *(const bf16x8*)&wm[(ct * 16 + l16) * LSTR + kk * 32 + quad * 8];
      acc[ct] = __builtin_amdgcn_mfma_f32_16x16x32_bf16(a, b, acc[ct], 0, 0, 0);
    }
  }
  __syncthreads();
  for (int ct = 0; ct < 8; ++ct) {
    const int o = ct * 16 + l16;
    const float bias = b_msg[o];
    for (int r = 0; r < 4; ++r)
      wm[o * 72 + rt * 16 + quad * 4 + r] = f2bf(fmaxf(acc[ct][r] + bias, 0.0f));
  }
  __syncthreads();
  for (int i = t; i < 1024; i += 256) {
    const int o = i >> 3, seg = i & 7;
    *(int4*)&msgT[o * NN + m0 + seg * 8] = *(const int4*)&wm[o * 72 + seg * 8];
  }
}

// ---------------- K2 v3
__global__ __launch_bounds__(256, 4) void k2_agg(
    const int* __restrict__ adj, const unsigned short* __restrict__ msgT,
    float* __restrict__ part, int* __restrict__ degp) {
  __shared__ unsigned short bT[2][128 * 64];  // [o][k-chunk swizzled], 16 KB each
  const int t = threadIdx.x;
  const int mt = blockIdx.x >> 3, split = blockIdx.x & 7;
  const int m0 = mt * 64, kb = split * 1024;
  const int lane = t & 63, wave = t >> 6;
  const int quad = lane >> 4, l16 = lane & 15;
  const int row = m0 + wave * 16 + l16;

  const int4* aB4 = (const int4*)(adj + (size_t)row * NN + kb);
  const int so = t >> 1, sseg = (t & 1) * 4;        // B staging: o-row, chunk base
  const int4* bP4 = (const int4*)(msgT + (size_t)so * NN + kb);

  f32x4 acc[8];
#pragma unroll
  for (int j = 0; j < 8; ++j) acc[j] = (f32x4){0.f, 0.f, 0.f, 0.f};
  int deg = 0;
  int4 ca[4], pa[4], pb[4];

  // prologue: stage step 0
#pragma unroll
  for (int j = 0; j < 4; ++j) pb[j] = bP4[sseg + j];
#pragma unroll
  for (int kk = 0; kk < 2; ++kk)
#pragma unroll
    for (int p = 0; p < 2; ++p) ca[kk * 2 + p] = aB4[kk * 8 + quad * 2 + p];
#pragma unroll
  for (int j = 0; j < 4; ++j) *(int4*)&bT[0][ldsOff(so, sseg + j)] = pb[j];
  __syncthreads();

  for (int s = 0; s < NSTEP; ++s) {
    const int buf = s & 1;
    if (s < NSTEP - 1) {  // issue next step's global loads first (independent batch)
      const int bo = (s + 1) * 8, ao = (s + 1) * 16;
#pragma unroll
      for (int j = 0; j < 4; ++j) pb[j] = bP4[bo + sseg + j];
#pragma unroll
      for (int kk = 0; kk < 2; ++kk)
#pragma unroll
        for (int p = 0; p < 2; ++p) pa[kk * 2 + p] = aB4[ao + kk * 8 + quad * 2 + p];
    }
#pragma unroll
    for (int kk = 0; kk < 2; ++kk) {
      union { bf16x8 v; unsigned short u[8]; } a;
      const int4 x0 = ca[kk * 2], x1 = ca[kk * 2 + 1];
      a.u[0] = x0.x ? 0x3F80 : 0; a.u[1] = x0.y ? 0x3F80 : 0;
      a.u[2] = x0.z ? 0x3F80 : 0; a.u[3] = x0.w ? 0x3F80 : 0;
      a.u[4] = x1.x ? 0x3F80 : 0; a.u[5] = x1.y ? 0x3F80 : 0;
      a.u[6] = x1.z ? 0x3F80 : 0; a.u[7] = x1.w ? 0x3F80 : 0;
      deg += x0.x + x0.y + x0.z + x0.w + x1.x + x1.y + x1.z + x1.w;
#pragma unroll
      for (int ct = 0; ct < 8; ++ct) {
        bf16x8 b = *(const bf16x8*)&bT[buf][ldsOff(ct * 16 + l16, kk * 4 + quad)];
        acc[ct] = __builtin_amdgcn_mfma_f32_16x16x32_bf16(a.v, b, acc[ct], 0, 0, 0);
      }
    }
    if (s < NSTEP - 1) {  // ds_write forces the B prefetch to have been issued
#pragma unroll
      for (int j = 0; j < 4; ++j) *(int4*)&bT[buf ^ 1][ldsOff(so, sseg + j)] = pb[j];
#pragma unroll
      for (int q = 0; q < 4; ++q) ca[q] = pa[q];
    }
    __syncthreads();
  }
  // degree: quads hold k-partials of row l16 within this split's K-range
  deg += __shfl_xor(deg, 16, 64);
  deg += __shfl_xor(deg, 32, 64);
  if (lane < 16) degp[split * NN + m0 + wave * 16 + lane] = deg;
  float* pp = part + (size_t)split * NN * DIM;
#pragma unroll
  for (int ct = 0; ct < 8; ++ct)
    for (int r = 0; r < 4; ++r)
      pp[(m0 + wave * 16 + quad * 4 + r) * DIM + ct * 16 + l16] = acc[ct][r];
}

// ---------------- K3: fused GRU; agg assembled from 8 fp32 partials + degree.
__global__ __launch_bounds__(256) void k3_gru(
    const float* __restrict__ nf, const float* __restrict__ part,
    const int* __restrict__ degp,
    const float* __restrict__ w_ih, const float* __restrict__ w_hh,
    const float* __restrict__ b_ih, const float* __restrict__ b_hh,
    float* __restrict__ out) {
  __shared__ unsigned short aggL[32 * LSTR];
  __shared__ unsigned short nfL[32 * LSTR];
  __shared__ unsigned short wL[128 * LSTR];
  __shared__ float invD[32];
  const int t = threadIdx.x;
  const int m0 = blockIdx.x * 32;
  if (t < 32) {
    int d = 0;
    for (int sp = 0; sp < KSPLIT; ++sp) d += degp[sp * NN + m0 + t];
    invD[t] = 1.0f / (float)(d > 1 ? d : 1);
  }
  __syncthreads();
  const float4* p4 = (const float4*)part;
  const float4* nf4 = (const float4*)nf;
  for (int u = t; u < 1024; u += 256) {   // 32 rows x 32 float4
    const int m = u >> 5;
    const int gi = (m0 + m) * 32 + (u & 31);
    float4 s = p4[gi];
    for (int sp = 1; sp < KSPLIT; ++sp) {
      float4 q = p4[sp * (NN * DIM / 4) + gi];
      s.x += q.x; s.y += q.y; s.z += q.z; s.w += q.w;
    }
    const float iv = invD[m];
    s.x *= iv; s.y *= iv; s.z *= iv; s.w *= iv;
    pack4(s, &aggL[m * LSTR + (u & 31) * 4]);
  }
  for (int u = t; u < 1024; u += 256) {
    const int m = u >> 5;
    pack4(nf4[(m0 + m) * 32 + (u & 31)], &nfL[m * LSTR + (u & 31) * 4]);
  }

  const int lane = t & 63, wave = t >> 6;
  const int quad = lane >> 4, l16 = lane & 15;
  const int rt = wave >> 1;
  const int cb = (wave & 1) * 4;
  const int aOff = (rt * 16 + l16) * LSTR + quad * 8;
  const float4* wih4 = (const float4*)w_ih;
  const float4* whh4 = (const float4*)w_hh;

  float gate[4][4];
  const int order[3] = {0, 2, 1};  // r -> n -> z
  for (int ci = 0; ci < 3; ++ci) {
    const int c = order[ci];
    __syncthreads();
    for (int u = t; u < 4096; u += 256)
      pack4(wih4[c * 4096 + u], &wL[(u >> 5) * LSTR + (u & 31) * 4]);
    __syncthreads();
    f32x4 ai[4];
    {
      bf16x8 a[4];
      for (int kk = 0; kk < 4; ++kk) a[kk] = *(const bf16x8*)&aggL[aOff + kk * 32];
      for (int j = 0; j < 4; ++j) {
        f32x4 acc = (f32x4){0.f, 0.f, 0.f, 0.f};
        const int ct = cb + j;
        for (int kk = 0; kk < 4; ++kk) {
          bf16x8 b = *(const bf16x8*)&wL[(ct * 16 + l16) * LSTR + kk * 32 + quad * 8];
          acc = __builtin_amdgcn_mfma_f32_16x16x32_bf16(a[kk], b, acc, 0, 0, 0);
        }
        ai[j] = acc;
      }
    }
    __syncthreads();
    for (int u = t; u < 4096; u += 256)
      pack4(whh4[c * 4096 + u], &wL[(u >> 5) * LSTR + (u & 31) * 4]);
    __syncthreads();
    f32x4 ah[4];
    {
      bf16x8 a[4];
      for (int kk = 0; kk < 4; ++kk) a[kk] = *(const bf16x8*)&nfL[aOff + kk * 32];
      for (int j = 0; j < 4; ++j) {
        f32x4 acc = (f32x4){0.f, 0.f, 0.f, 0.f};
        const int ct = cb + j;
        for (int kk = 0; kk < 4; ++kk) {
          bf16x8 b = *(const bf16x8*)&wL[(ct * 16 + l16) * LSTR + kk * 32 + quad * 8];
          acc = __builtin_amdgcn_mfma_f32_16x16x32_bf16(a[kk], b, acc, 0, 0, 0);
        }
        ah[j] = acc;
      }
    }
    for (int j = 0; j < 4; ++j) {
      const int col = (cb + j) * 16 + l16;
      const float bi = b_ih[c * 128 + col];
      const float bh = b_hh[c * 128 + col];
      for (int r = 0; r < 4; ++r) {
        const float gi = ai[j][r] + bi;
        const float gh = ah[j][r] + bh;
        if (c == 0) {
          gate[j][r] = sigmoidf_(gi + gh);
        } else if (c == 2) {
          gate[j][r] = tanhf_(gi + gate[j][r] * gh);
        } else {
          const float z = sigmoidf_(gi + gh);
          const int m = m0 + rt * 16 + quad * 4 + r;
          const float h = nf[m * 128 + col];
          out[m * 128 + col] = (1.0f - z) * gate[j][r] + z * h;
        }
      }
    }
  }
}

extern "C" void kernel_launch(void* const* d_in, const int* in_sizes, int n_in,
                              void* d_out, int out_size, void* d_ws, size_t ws_size,
                              hipStream_t stream) {
  const float* nf   = (const float*)d_in[0];
  const int*   adj  = (const int*)d_in[1];
  const float* wmsg = (const float*)d_in[2];
  const float* bmsg = (const float*)d_in[3];
  const float* wih  = (const float*)d_in[4];
  const float* whh  = (const float*)d_in[5];
  const float* bih  = (const float*)d_in[6];
  const float* bhh  = (const float*)d_in[7];
  float* out = (float*)d_out;

  char* ws = (char*)d_ws;
  unsigned short* msgT = (unsigned short*)ws;              // bf16 [128][8192]      2 MB
  float* part = (float*)(ws + (size_t)2 * 1024 * 1024);    // f32 [8][8192][128]   32 MB
  int* degp   = (int*)(ws + (size_t)34 * 1024 * 1024);     // int [8][8192]       256 KB

  k1_msg<<<NN / 64, 256, 0, stream>>>(nf, wmsg, bmsg, msgT);
  k2_agg<<<(NN / 64) * KSPLIT, 256, 0, stream>>>(adj, msgT, part, degp);
  k3_gru<<<NN / 32, 256, 0, stream>>>(nf, part, degp, wih, whh, bih, bhh, out);
}

// Round 4
// 455.090 us; speedup vs baseline: 1.1731x; 1.0058x over previous
//
#include <hip/hip_runtime.h>

// GNN layer: messages = relu(NF @ Wm^T + bm); agg = (adj @ messages)/deg; GRU(agg, NF)
// N=8192, D=128. k2 memory-bound on adj (268 MB int32) -> ~43 us floor.
// k2 v4 (m97-style): global_load_lds width=16 for BOTH A(int32 adj) and B(msgT bf16),
// double-buffered, one barrier per step. No register landing -> compiler cannot
// serialize/sink the staging loads (rounds 2-3 failure mode). LDS dest must be
// lane-linear (wave-uniform base + lane*16), so bank conflicts are broken by
// XOR-permuting chunk order on the GLOBAL side: c_stored = c_logical ^ (row&7).

#define NN 8192
#define DIM 128
#define LSTR 136     // k1/k3 LDS row stride (shorts)
#define KSPLIT 4
#define NSTEP 32     // (8192/KSPLIT)/64 steps of K=64

typedef __bf16 bf16x8 __attribute__((ext_vector_type(8)));
typedef float f32x4 __attribute__((ext_vector_type(4)));

__device__ __forceinline__ unsigned short f2bf(float f) {
  union { float f; unsigned u; } v; v.f = f;
  unsigned r = v.u + 0x7FFF + ((v.u >> 16) & 1);  // RNE
  return (unsigned short)(r >> 16);
}
__device__ __forceinline__ float sigmoidf_(float x) {
  return 1.0f / (1.0f + __expf(-x));
}
__device__ __forceinline__ float tanhf_(float x) {
  float e = __expf(-2.0f * fabsf(x));
  float r = (1.0f - e) / (1.0f + e);
  return x < 0.0f ? -r : r;
}
__device__ __forceinline__ void pack4(float4 v, unsigned short* dst) {
  dst[0] = f2bf(v.x); dst[1] = f2bf(v.y); dst[2] = f2bf(v.z); dst[3] = f2bf(v.w);
}
// async 16B/lane global->LDS DMA; lds dest must be wave-uniform (HW adds lane*16)
__device__ __forceinline__ void async16(const void* g, void* l) {
  __builtin_amdgcn_global_load_lds(
      (const __attribute__((address_space(1))) unsigned int*)g,
      (__attribute__((address_space(3))) unsigned int*)l, 16, 0, 0);
}

// ---------------- K1: msgT[o][m] = relu(NF @ Wm^T + bm) bf16, coalesced stores
__global__ __launch_bounds__(256) void k1_msg(
    const float* __restrict__ nf, const float* __restrict__ w_msg,
    const float* __restrict__ b_msg, unsigned short* __restrict__ msgT) {
  __shared__ unsigned short wm[128 * LSTR];   // wm[o][k]; reused as T[o][m] (stride 72)
  __shared__ unsigned short nfl[64 * LSTR];
  const int t = threadIdx.x;
  const int m0 = blockIdx.x * 64;
  const float4* wm4 = (const float4*)w_msg;
  const float4* nf4 = (const float4*)nf;
  for (int i = t; i < 4096; i += 256)
    pack4(wm4[i], &wm[(i >> 5) * LSTR + (i & 31) * 4]);
  for (int i = t; i < 2048; i += 256)
    pack4(nf4[m0 * 32 + i], &nfl[(i >> 5) * LSTR + (i & 31) * 4]);
  __syncthreads();
  const int lane = t & 63, wave = t >> 6;
  const int quad = lane >> 4, l16 = lane & 15;
  const int rt = wave;
  f32x4 acc[8];
  for (int j = 0; j < 8; ++j) acc[j] = (f32x4){0.f, 0.f, 0.f, 0.f};
  for (int kk = 0; kk < 4; ++kk) {
    bf16x8 a = *(const bf16x8*)&nfl[(rt * 16 + l16) * LSTR + kk * 32 + quad * 8];
    for (int ct = 0; ct < 8; ++ct) {
      bf16x8 b = *(const bf16x8*)&wm[(ct * 16 + l16) * LSTR + kk * 32 + quad * 8];
      acc[ct] = __builtin_amdgcn_mfma_f32_16x16x32_bf16(a, b, acc[ct], 0, 0, 0);
    }
  }
  __syncthreads();
  for (int ct = 0; ct < 8; ++ct) {
    const int o = ct * 16 + l16;
    const float bias = b_msg[o];
    for (int r = 0; r < 4; ++r)
      wm[o * 72 + rt * 16 + quad * 4 + r] = f2bf(fmaxf(acc[ct][r] + bias, 0.0f));
  }
  __syncthreads();
  for (int i = t; i < 1024; i += 256) {
    const int o = i >> 3, seg = i & 7;
    *(int4*)&msgT[o * NN + m0 + seg * 8] = *(const int4*)&wm[o * 72 + seg * 8];
  }
}

// ---------------- K2 v4: async global->LDS double buffer
__global__ __launch_bounds__(256, 2) void k2_agg(
    const int* __restrict__ adj, const unsigned short* __restrict__ msgT,
    float* __restrict__ part, int* __restrict__ degp) {
  __shared__ int aT[2][64 * 64];              // [m][perm k-chunks], 16 KB/buf
  __shared__ unsigned short bT[2][128 * 64];  // [o][perm k-chunks], 16 KB/buf
  const int t = threadIdx.x;
  const int lane = t & 63, wave = t >> 6;
  const int quad = lane >> 4, l16 = lane & 15, sw = l16 & 7;
  const int mt = blockIdx.x >> 2, split = blockIdx.x & 3;
  const int m0 = mt * 64, kb = split * (NN / KSPLIT);

  // per-lane staging source descriptors (LDS side is lane-linear, set by HW)
  const int* aSrc[4];
  const unsigned short* bSrc[4];
  int aLds[4], bLds[4];
#pragma unroll
  for (int j = 0; j < 4; ++j) {
    const int seg = wave * 4 + j;                 // 0..15
    const int ra = seg * 4 + (lane >> 4);         // A row_local 0..63 (4 rows/issue)
    const int ca = (lane & 15) ^ (ra & 7);        // logical 16B chunk (4 ints)
    aSrc[j] = adj + (size_t)(m0 + ra) * NN + kb + ca * 4;
    aLds[j] = seg * 1024;                         // byte offset (uniform per wave)
    const int ob = seg * 8 + (lane >> 3);         // B row o 0..127 (8 rows/issue)
    const int cb = (lane & 7) ^ (ob & 7);         // logical 16B chunk (8 shorts)
    bSrc[j] = msgT + (size_t)ob * NN + kb + cb * 8;
    bLds[j] = seg * 1024;
  }

  f32x4 acc[8];
#pragma unroll
  for (int j = 0; j < 8; ++j) acc[j] = (f32x4){0.f, 0.f, 0.f, 0.f};
  int deg = 0;

  // prologue: stage step 0 into buf 0
#pragma unroll
  for (int j = 0; j < 4; ++j) async16(aSrc[j], (char*)&aT[0][0] + aLds[j]);
#pragma unroll
  for (int j = 0; j < 4; ++j) async16(bSrc[j], (char*)&bT[0][0] + bLds[j]);

  const int aBase = (wave * 16 + l16) * 64;       // int index of this lane's A row

  for (int s = 0; s < NSTEP; ++s) {
    const int buf = s & 1;
    __syncthreads();  // drains vmcnt(0): buf's staged data ready; buf^1 free
    if (s + 1 < NSTEP) {  // fire-and-forget next step (no dest reg -> can't sink)
      const int ko = (s + 1) * 64;
#pragma unroll
      for (int j = 0; j < 4; ++j)
        async16(aSrc[j] + ko, (char*)&aT[buf ^ 1][0] + aLds[j]);
#pragma unroll
      for (int j = 0; j < 4; ++j)
        async16(bSrc[j] + ko, (char*)&bT[buf ^ 1][0] + bLds[j]);
    }
#pragma unroll
    for (int kk = 0; kk < 2; ++kk) {
      const int c0 = kk * 8 + quad * 2;
      int4 A0 = *(const int4*)&aT[buf][aBase + ((c0 ^ sw) << 2)];
      int4 A1 = *(const int4*)&aT[buf][aBase + (((c0 + 1) ^ sw) << 2)];
      union { bf16x8 v; unsigned short u[8]; } a;
      a.u[0] = A0.x ? 0x3F80 : 0; a.u[1] = A0.y ? 0x3F80 : 0;
      a.u[2] = A0.z ? 0x3F80 : 0; a.u[3] = A0.w ? 0x3F80 : 0;
      a.u[4] = A1.x ? 0x3F80 : 0; a.u[5] = A1.y ? 0x3F80 : 0;
      a.u[6] = A1.z ? 0x3F80 : 0; a.u[7] = A1.w ? 0x3F80 : 0;
      deg += A0.x + A0.y + A0.z + A0.w + A1.x + A1.y + A1.z + A1.w;
#pragma unroll
      for (int ct = 0; ct < 8; ++ct) {
        bf16x8 b = *(const bf16x8*)
            &bT[buf][(ct * 16 + l16) * 64 + (((kk * 4 + quad) ^ sw) << 3)];
        acc[ct] = __builtin_amdgcn_mfma_f32_16x16x32_bf16(a.v, b, acc[ct], 0, 0, 0);
      }
    }
  }
  // degree: quads hold k-partials of row wave*16+l16 within this split's range
  deg += __shfl_xor(deg, 16, 64);
  deg += __shfl_xor(deg, 32, 64);
  if (lane < 16) degp[split * NN + m0 + wave * 16 + lane] = deg;
  float* pp = part + (size_t)split * NN * DIM;
#pragma unroll
  for (int ct = 0; ct < 8; ++ct)
    for (int r = 0; r < 4; ++r)
      pp[(m0 + wave * 16 + quad * 4 + r) * DIM + ct * 16 + l16] = acc[ct][r];
}

// ---------------- K3: fused GRU; agg assembled from KSPLIT fp32 partials + degree.
__global__ __launch_bounds__(256) void k3_gru(
    const float* __restrict__ nf, const float* __restrict__ part,
    const int* __restrict__ degp,
    const float* __restrict__ w_ih, const float* __restrict__ w_hh,
    const float* __restrict__ b_ih, const float* __restrict__ b_hh,
    float* __restrict__ out) {
  __shared__ unsigned short aggL[32 * LSTR];
  __shared__ unsigned short nfL[32 * LSTR];
  __shared__ unsigned short wL[128 * LSTR];
  __shared__ float invD[32];
  const int t = threadIdx.x;
  const int m0 = blockIdx.x * 32;
  if (t < 32) {
    int d = 0;
    for (int sp = 0; sp < KSPLIT; ++sp) d += degp[sp * NN + m0 + t];
    invD[t] = 1.0f / (float)(d > 1 ? d : 1);
  }
  __syncthreads();
  const float4* p4 = (const float4*)part;
  const float4* nf4 = (const float4*)nf;
  for (int u = t; u < 1024; u += 256) {   // 32 rows x 32 float4
    const int m = u >> 5;
    const int gi = (m0 + m) * 32 + (u & 31);
    float4 s = p4[gi];
    for (int sp = 1; sp < KSPLIT; ++sp) {
      float4 q = p4[sp * (NN * DIM / 4) + gi];
      s.x += q.x; s.y += q.y; s.z += q.z; s.w += q.w;
    }
    const float iv = invD[m];
    s.x *= iv; s.y *= iv; s.z *= iv; s.w *= iv;
    pack4(s, &aggL[m * LSTR + (u & 31) * 4]);
  }
  for (int u = t; u < 1024; u += 256) {
    const int m = u >> 5;
    pack4(nf4[(m0 + m) * 32 + (u & 31)], &nfL[m * LSTR + (u & 31) * 4]);
  }

  const int lane = t & 63, wave = t >> 6;
  const int quad = lane >> 4, l16 = lane & 15;
  const int rt = wave >> 1;
  const int cb = (wave & 1) * 4;
  const int aOff = (rt * 16 + l16) * LSTR + quad * 8;
  const float4* wih4 = (const float4*)w_ih;
  const float4* whh4 = (const float4*)w_hh;

  float gate[4][4];
  const int order[3] = {0, 2, 1};  // r -> n -> z
  for (int ci = 0; ci < 3; ++ci) {
    const int c = order[ci];
    __syncthreads();
    for (int u = t; u < 4096; u += 256)
      pack4(wih4[c * 4096 + u], &wL[(u >> 5) * LSTR + (u & 31) * 4]);
    __syncthreads();
    f32x4 ai[4];
    {
      bf16x8 a[4];
      for (int kk = 0; kk < 4; ++kk) a[kk] = *(const bf16x8*)&aggL[aOff + kk * 32];
      for (int j = 0; j < 4; ++j) {
        f32x4 acc = (f32x4){0.f, 0.f, 0.f, 0.f};
        const int ct = cb + j;
        for (int kk = 0; kk < 4; ++kk) {
          bf16x8 b = *(const bf16x8*)&wL[(ct * 16 + l16) * LSTR + kk * 32 + quad * 8];
          acc = __builtin_amdgcn_mfma_f32_16x16x32_bf16(a[kk], b, acc, 0, 0, 0);
        }
        ai[j] = acc;
      }
    }
    __syncthreads();
    for (int u = t; u < 4096; u += 256)
      pack4(whh4[c * 4096 + u], &wL[(u >> 5) * LSTR + (u & 31) * 4]);
    __syncthreads();
    f32x4 ah[4];
    {
      bf16x8 a[4];
      for (int kk = 0; kk < 4; ++kk) a[kk] = *(const bf16x8*)&nfL[aOff + kk * 32];
      for (int j = 0; j < 4; ++j) {
        f32x4 acc = (f32x4){0.f, 0.f, 0.f, 0.f};
        const int ct = cb + j;
        for (int kk = 0; kk < 4; ++kk) {
          bf16x8 b = *(const bf16x8*)&wL[(ct * 16 + l16) * LSTR + kk * 32 + quad * 8];
          acc = __builtin_amdgcn_mfma_f32_16x16x32_bf16(a[kk], b, acc, 0, 0, 0);
        }
        ah[j] = acc;
      }
    }
    for (int j = 0; j < 4; ++j) {
      const int col = (cb + j) * 16 + l16;
      const float bi = b_ih[c * 128 + col];
      const float bh = b_hh[c * 128 + col];
      for (int r = 0; r < 4; ++r) {
        const float gi = ai[j][r] + bi;
        const float gh = ah[j][r] + bh;
        if (c == 0) {
          gate[j][r] = sigmoidf_(gi + gh);
        } else if (c == 2) {
          gate[j][r] = tanhf_(gi + gate[j][r] * gh);
        } else {
          const float z = sigmoidf_(gi + gh);
          const int m = m0 + rt * 16 + quad * 4 + r;
          const float h = nf[m * 128 + col];
          out[m * 128 + col] = (1.0f - z) * gate[j][r] + z * h;
        }
      }
    }
  }
}

extern "C" void kernel_launch(void* const* d_in, const int* in_sizes, int n_in,
                              void* d_out, int out_size, void* d_ws, size_t ws_size,
                              hipStream_t stream) {
  const float* nf   = (const float*)d_in[0];
  const int*   adj  = (const int*)d_in[1];
  const float* wmsg = (const float*)d_in[2];
  const float* bmsg = (const float*)d_in[3];
  const float* wih  = (const float*)d_in[4];
  const float* whh  = (const float*)d_in[5];
  const float* bih  = (const float*)d_in[6];
  const float* bhh  = (const float*)d_in[7];
  float* out = (float*)d_out;

  char* ws = (char*)d_ws;
  unsigned short* msgT = (unsigned short*)ws;              // bf16 [128][8192]     2 MB
  float* part = (float*)(ws + (size_t)2 * 1024 * 1024);    // f32 [4][8192][128]  16 MB
  int* degp   = (int*)(ws + (size_t)18 * 1024 * 1024);     // int [4][8192]      128 KB

  k1_msg<<<NN / 64, 256, 0, stream>>>(nf, wmsg, bmsg, msgT);
  k2_agg<<<(NN / 64) * KSPLIT, 256, 0, stream>>>(adj, msgT, part, degp);
  k3_gru<<<NN / 32, 256, 0, stream>>>(nf, part, degp, wih, whh, bih, bhh, out);
}